// Round 4
// baseline (1786.939 us; speedup 1.0000x reference)
//
#include <hip/hip_runtime.h>
#include <math.h>

typedef float vf4 __attribute__((ext_vector_type(4)));

#define CODE_SIZE 1024
#define CODE_DIM  256
#define BB        64
#define HWSZ      1024                       // H*W = 32*32
#define NROWS     (BB * HWSZ)                // 65536
#define QELEMS    (BB * CODE_DIM * HWSZ)     // 16777216

// ---------------------------------------------------------------------------
// sw[code] = numpy-pairwise sum of fl(w*w) over 256 contiguous elements.
// ---------------------------------------------------------------------------
__global__ void k_sumsq_w(const float* __restrict__ w, float* __restrict__ sw) {
#pragma clang fp contract(off)
  const int code = blockIdx.x * blockDim.x + threadIdx.x;
  if (code >= CODE_SIZE) return;
  const float* row = w + (size_t)code * CODE_DIM;
  float halves[2];
  for (int h = 0; h < 2; ++h) {
    const float* p = row + h * 128;
    float r[8];
#pragma unroll
    for (int j = 0; j < 8; ++j) { float v = p[j]; r[j] = v * v; }
    for (int i = 8; i < 128; i += 8) {
#pragma unroll
      for (int j = 0; j < 8; ++j) { float v = p[i + j]; r[j] += v * v; }
    }
    halves[h] = ((r[0] + r[1]) + (r[2] + r[3])) + ((r[4] + r[5]) + (r[6] + r[7]));
  }
  sw[code] = halves[0] + halves[1];
}

// sx[n] = same pairwise over fl(x*x), x strided by HWSZ along channel dim.
__global__ void k_sumsq_x(const float* __restrict__ x, float* __restrict__ sx) {
#pragma clang fp contract(off)
  const int n = blockIdx.x * blockDim.x + threadIdx.x;   // 0..65535
  const int b = n >> 10, hw = n & 1023;
  const float* p = x + (size_t)b * CODE_DIM * HWSZ + hw;
  float halves[2];
  for (int h = 0; h < 2; ++h) {
    const float* q = p + (size_t)(h * 128) * HWSZ;
    float r[8];
#pragma unroll
    for (int j = 0; j < 8; ++j) { float v = q[(size_t)j * HWSZ]; r[j] = v * v; }
    for (int i = 8; i < 128; i += 8) {
#pragma unroll
      for (int j = 0; j < 8; ++j) { float v = q[(size_t)(i + j) * HWSZ]; r[j] += v * v; }
    }
    halves[h] = ((r[0] + r[1]) + (r[2] + r[3])) + ((r[4] + r[5]) + (r[6] + r[7]));
  }
  sx[n] = halves[0] + halves[1];
}

// ---------------------------------------------------------------------------
// GEMM-argmin v3b: lane = row, wave-uniform codes, NO operand LDS.
// Rounds 0-2 were DS-throughput-bound: per CU per k-step, 12 waves x 4
// ds_read_b128 x ~12cy = 576 cy DS vs 384 cy VALU-issue -> VALUBusy 66.6%
// (= 384/576 exactly). Fix: remove LDS from the operand path.
//  - x: lane l = row n0+l; per kc-step, KC coalesced global dword loads
//    (lanes are consecutive floats of x[b][k][hw0..hw0+63]) into xk[] regs.
//  - w: code index is wave-uniform (readfirstlane(t>>6)) -> w[code][k] vf4
//    loads are uniform -> scalar s_load into SGPRs (SMEM pipe); v_fmac takes
//    the one legal SGPR operand. w is 1 MB, L2-resident.
//  - DS: only a 2 KB final cross-wave reduction buffer.
// v3b vs failed v3 submit: KC 32->16 and vf4 w loads — kc body shrinks from
// ~4.5k to ~1.3k instrs (compile-time/RA de-risk; round-3 bench died with no
// counters, possibly harness timeout on the huge straight-line block).
// Numerics: acc[c] is a single sequential fmaf chain over k=0..255 ascending
// (kc-outer, k-inner) — bitwise-matching rounds 0/2 (absmax 0.0).
// Key = fl(fl(sx-2G)+sw), contract off (2*acc exact). Codes ascending per
// lane; merge lexicographic (key, idx) -> lowest-index tie-break preserved.
// All acc[]/xk[] loops fully unrolled (runtime-indexed regs -> scratch).
// VGPR: acc 64 + xk 16 + addr ~= 105; (256,3) caps alloc at 168 -> no spill
// (round-1 lesson: (256,4)'s 128 cap spilled a ~140-reg working set).
// ---------------------------------------------------------------------------
#define MT     64
#define NCH    4      // code chunks of 256
#define WCODES 64     // codes per wave per chunk
#define KC     16

__launch_bounds__(256, 3)
__global__ void k_argmin(const float* __restrict__ x, const float* __restrict__ w,
                         const float* __restrict__ sx, const float* __restrict__ sw,
                         float* __restrict__ oidx) {
  __shared__ float redk[4][MT];
  __shared__ float redi[4][MT];

  const int t    = threadIdx.x;
  const int lane = t & 63;
  const int wv   = __builtin_amdgcn_readfirstlane(t >> 6);   // 0..3, uniform
  const int n0   = blockIdx.x * MT;
  const int b    = n0 >> 10;
  const int hw0  = n0 & 1023;

  const float* xlane = x + (size_t)b * CODE_DIM * HWSZ + hw0 + lane;
  const float  sxr   = sx[n0 + lane];

  float bk = INFINITY, bi = (float)CODE_SIZE;

  for (int chunk = 0; chunk < NCH; ++chunk) {
    const int code0 = chunk * (NCH * WCODES) + wv * WCODES;  // wave's 64 codes

    float acc[WCODES];
#pragma unroll
    for (int c = 0; c < WCODES; ++c) acc[c] = 0.0f;

    for (int kc = 0; kc < CODE_DIM / KC; ++kc) {
      const int kbase = kc * KC;

      // KC coalesced global loads: lanes span consecutive hw -> 256-B/wave
      float xk[KC];
#pragma unroll
      for (int k = 0; k < KC; ++k)
        xk[k] = xlane[(size_t)(kbase + k) * HWSZ];

      // wave-uniform w rows, vf4 (s_load_dwordx4-shaped) -> SGPR operands
#pragma unroll
      for (int c = 0; c < WCODES; ++c) {
        const float* wr = w + (size_t)(code0 + c) * CODE_DIM + kbase;
#pragma unroll
        for (int q = 0; q < KC / 4; ++q) {
          const vf4 wq = *(const vf4*)(wr + q * 4);
          acc[c] = fmaf(xk[q * 4 + 0], wq.x, acc[c]);
          acc[c] = fmaf(xk[q * 4 + 1], wq.y, acc[c]);
          acc[c] = fmaf(xk[q * 4 + 2], wq.z, acc[c]);
          acc[c] = fmaf(xk[q * 4 + 3], wq.w, acc[c]);
        }
      }
    }

    // merge, codes ascending (strict < keeps lowest index)
    {
#pragma clang fp contract(off)
#pragma unroll
      for (int c = 0; c < WCODES; ++c) {
        const int   code  = code0 + c;
        const float tmp   = sxr - 2.0f * acc[c];   // fl(sx - 2G) (2*acc exact)
        const float key   = tmp + sw[code];        // fl(.. + sw)
        const float codef = (float)code;
        if (key < bk || (key == bk && codef < bi)) { bk = key; bi = codef; }
      }
    }
  }

  // cross-wave reduction: waves hold disjoint code sets for the same 64 rows
  redk[wv][lane] = bk;
  redi[wv][lane] = bi;
  __syncthreads();
  if (t < MT) {
    float k0 = redk[0][t], i0 = redi[0][t];
#pragma unroll
    for (int q = 1; q < 4; ++q) {
      const float kq = redk[q][t];
      const float iq = redi[q][t];
      if (kq < k0 || (kq == k0 && iq < i0)) { k0 = kq; i0 = iq; }
    }
    oidx[n0 + t] = i0;   // idx output region read back as fp32
  }
}

// ---------------------------------------------------------------------------
// Epilogue: block = (b, 64-hw tile). Stage the 64 gathered w-rows into LDS
// (wt[c][r], stride 65 -> 2-way banks, free), then fully-coalesced vf4
// global reads/writes for q and ste = fl(fl(q - x) + x).
// ---------------------------------------------------------------------------
#define WT_S 65

__global__ void k_epilogue(const float* __restrict__ x, const float* __restrict__ w,
                           const float* __restrict__ oidx, float* __restrict__ out) {
#pragma clang fp contract(off)
  __shared__ int   idxs[MT];
  __shared__ float wt[CODE_DIM * WT_S];   // wt[c][r], 66560 B

  const int t   = threadIdx.x;
  const int n0  = blockIdx.x * MT;
  const int b   = n0 >> 10;
  const int hw0 = n0 & 1023;

  if (t < MT) idxs[t] = (int)oidx[n0 + t];
  __syncthreads();

  // stage wt: jobs j -> (r = j&63, cq = j>>6); lanes span r -> per-lane 16-B
  // gathers from 64 w-rows (L1/L2 absorb; each row consumed fully by the
  // 4 sibling threads), LDS writes bank=(c+r)%32 with r spanning -> free.
#pragma unroll
  for (int i = 0; i < 16; ++i) {
    const int j  = t + 256 * i;
    const int r  = j & 63;
    const int cq = j >> 6;     // 0..63
    vf4 v = *(const vf4*)(w + (size_t)idxs[r] * CODE_DIM + cq * 4);
    wt[(cq * 4 + 0) * WT_S + r] = v.x;
    wt[(cq * 4 + 1) * WT_S + r] = v.y;
    wt[(cq * 4 + 2) * WT_S + r] = v.z;
    wt[(cq * 4 + 3) * WT_S + r] = v.w;
  }
  __syncthreads();

  // outputs: jobs j -> (c = j>>4, rq = j&15); global vf4 fully coalesced
#pragma unroll
  for (int i = 0; i < 16; ++i) {
    const int j  = t + 256 * i;
    const int c  = j >> 4;     // 0..255
    const int rq = j & 15;
    const size_t off = (size_t)(b * CODE_DIM + c) * HWSZ + hw0 + rq * 4;
    vf4 xv = *(const vf4*)(x + off);
    vf4 q, s;
#pragma unroll
    for (int u = 0; u < 4; ++u) {
      const float qv = wt[c * WT_S + rq * 4 + u];
      q[u] = qv;
      const float d = qv - xv[u];
      s[u] = d + xv[u];
    }
    *(vf4*)(out + off) = q;
    *(vf4*)(out + (size_t)QELEMS + off) = s;
  }
}

extern "C" void kernel_launch(void* const* d_in, const int* in_sizes, int n_in,
                              void* d_out, int out_size, void* d_ws, size_t ws_size,
                              hipStream_t stream) {
  const float* x = (const float*)d_in[0];   // (64,256,32,32) fp32
  const float* w = (const float*)d_in[1];   // (1024,256) fp32
  float* out  = (float*)d_out;
  float* oidx = out + 2 * (size_t)QELEMS;          // idx region (written as float)
  // scratch for sx/sw lives inside the ste region; epilogue (which runs after
  // k_argmin completes, stream-ordered) overwrites it later
  float* sx = out + (size_t)QELEMS;                // 65536 floats
  float* sw = out + (size_t)QELEMS + NROWS;        // 1024 floats

  k_sumsq_w<<<CODE_SIZE / 256, 256, 0, stream>>>(w, sw);
  k_sumsq_x<<<NROWS / 256, 256, 0, stream>>>(x, sx);
  k_argmin<<<NROWS / MT, 256, 0, stream>>>(x, w, sx, sw, oidx);
  k_epilogue<<<NROWS / MT, 256, 0, stream>>>(x, w, oidx, out);
}

// Round 5
// 903.205 us; speedup vs baseline: 1.9784x; 1.9784x over previous
//
#include <hip/hip_runtime.h>
#include <math.h>

typedef float vf4 __attribute__((ext_vector_type(4)));

#define CODE_SIZE 1024
#define CODE_DIM  256
#define BB        64
#define HWSZ      1024                       // H*W = 32*32
#define NROWS     (BB * HWSZ)                // 65536
#define QELEMS    (BB * CODE_DIM * HWSZ)     // 16777216

// ---------------------------------------------------------------------------
// sw[code] = numpy-pairwise sum of fl(w*w) over 256 contiguous elements.
// ---------------------------------------------------------------------------
__global__ void k_sumsq_w(const float* __restrict__ w, float* __restrict__ sw) {
#pragma clang fp contract(off)
  const int code = blockIdx.x * blockDim.x + threadIdx.x;
  if (code >= CODE_SIZE) return;
  const float* row = w + (size_t)code * CODE_DIM;
  float halves[2];
  for (int h = 0; h < 2; ++h) {
    const float* p = row + h * 128;
    float r[8];
#pragma unroll
    for (int j = 0; j < 8; ++j) { float v = p[j]; r[j] = v * v; }
    for (int i = 8; i < 128; i += 8) {
#pragma unroll
      for (int j = 0; j < 8; ++j) { float v = p[i + j]; r[j] += v * v; }
    }
    halves[h] = ((r[0] + r[1]) + (r[2] + r[3])) + ((r[4] + r[5]) + (r[6] + r[7]));
  }
  sw[code] = halves[0] + halves[1];
}

// sx[n] = same pairwise over fl(x*x), x strided by HWSZ along channel dim.
__global__ void k_sumsq_x(const float* __restrict__ x, float* __restrict__ sx) {
#pragma clang fp contract(off)
  const int n = blockIdx.x * blockDim.x + threadIdx.x;   // 0..65535
  const int b = n >> 10, hw = n & 1023;
  const float* p = x + (size_t)b * CODE_DIM * HWSZ + hw;
  float halves[2];
  for (int h = 0; h < 2; ++h) {
    const float* q = p + (size_t)(h * 128) * HWSZ;
    float r[8];
#pragma unroll
    for (int j = 0; j < 8; ++j) { float v = q[(size_t)j * HWSZ]; r[j] = v * v; }
    for (int i = 8; i < 128; i += 8) {
#pragma unroll
      for (int j = 0; j < 8; ++j) { float v = q[(size_t)(i + j) * HWSZ]; r[j] += v * v; }
    }
    halves[h] = ((r[0] + r[1]) + (r[2] + r[3])) + ((r[4] + r[5]) + (r[6] + r[7]));
  }
  sx[n] = halves[0] + halves[1];
}

// ---------------------------------------------------------------------------
// GEMM-argmin v4: round-0 structure (proven 444 us, bitwise-exact) with x
// moved OUT of LDS. Round-0 was DS-throughput-bound: per CU per k-step,
// 12 waves x 4 ds_read_b128 x 12cy = 576 DS-cy vs 384 VALU-cy -> VALUBusy
// 66.6% (= 384/576). x's operand pattern per thread per k is 8 CONSECUTIVE
// floats x[b][k][hw0+rt*8..+7]: the wave covers one 256-B window (8-way
// same-address broadcast per rt group) -> 2 coalesced global dwordx4 per
// thread per k straight into the FMA. w keeps the ws[k][code] LDS tile
// (broadcast reads, conflict-free; global w would be a stride-256 gather).
// DS/CU/k: 12 x (2x12 + ~6 ws-write amortized) ~= 358 < VALU ~384-430 ->
// VALU-issue-bound.
// Round-4 lesson honored: NO >16-element per-thread acc arrays (v3's
// acc[64] was demoted to scratch, VGPR=56, 3.7x slower). acc stays 8x8.
// Numerics: bit-identical to round 0/2 — same x/w values into the same
// sequential fmaf chain (chunk-outer, kc-inner, k ascending), key =
// fl(fl(sx-2G)+sw) contract-off, ascending-code strict-< tie-break,
// identical cross-thread reduction. absmax must stay 0.0.
// LDS: ws 32 KB only (xs gone). VGPR ~110 under (256,3)'s 168 cap — no
// spill (round-1 lesson: (256,4)'s 128 cap spilled).
// ---------------------------------------------------------------------------
#define MT  64
#define NTC 256
#define NCH (CODE_SIZE / NTC)
#define KC  32

__launch_bounds__(256, 3)
__global__ void k_argmin(const float* __restrict__ x, const float* __restrict__ w,
                         const float* __restrict__ sx, const float* __restrict__ sw,
                         float* __restrict__ oidx) {
  __shared__ float ws[KC * NTC];   // [k][code], 32 KB; overlaid by reduction

  const int t   = threadIdx.x;
  const int n0  = blockIdx.x * MT;
  const int b   = n0 >> 10;
  const int hw0 = n0 & 1023;
  const int rt  = t & 7;     // rows rt*8 .. rt*8+7
  const int ct  = t >> 3;    // code-group 0..31: codes ct*8..ct*8+7 per chunk

  // x operand base: 8 consecutive floats per k for this thread's rows
  const float* xbase = x + (size_t)b * CODE_DIM * HWSZ + hw0 + rt * 8;

  float bk[8]; float bi[8];
#pragma unroll
  for (int ri = 0; ri < 8; ++ri) { bk[ri] = INFINITY; bi[ri] = (float)CODE_SIZE; }

  for (int chunk = 0; chunk < NCH; ++chunk) {
    const int code0 = chunk * NTC;

    float acc[8][8];
#pragma unroll
    for (int ri = 0; ri < 8; ++ri)
#pragma unroll
      for (int cj = 0; cj < 8; ++cj) acc[ri][cj] = 0.0f;

    for (int kc = 0; kc < CODE_DIM / KC; ++kc) {
      const int kbase = kc * KC;
      __syncthreads();   // protect ws from previous stage's readers
      // stage ws[k][code]: thread t owns code code0+t; row-contiguous global
      // reads (L2-hot, w is 1 MB), LDS writes bank = t mod 32; lanes t,t+32
      // same-bank-different-address -> 2-way, free
      {
        const float* wr = w + (size_t)(code0 + t) * CODE_DIM + kbase;
#pragma unroll
        for (int q = 0; q < 8; ++q) {
          vf4 v = *(const vf4*)(wr + q * 4);
          ws[(q * 4 + 0) * NTC + t] = v.x;
          ws[(q * 4 + 1) * NTC + t] = v.y;
          ws[(q * 4 + 2) * NTC + t] = v.z;
          ws[(q * 4 + 3) * NTC + t] = v.w;
        }
      }
      __syncthreads();

      const float* xp = xbase + (size_t)kbase * HWSZ;
      const float* wp = ws + ct * 8;
#pragma unroll 4
      for (int k = 0; k < KC; ++k) {
        vf4 xv0 = *(const vf4*)(xp + (size_t)k * HWSZ);
        vf4 xv1 = *(const vf4*)(xp + (size_t)k * HWSZ + 4);
        vf4 wv0 = *(const vf4*)(wp + k * NTC);
        vf4 wv1 = *(const vf4*)(wp + k * NTC + 4);
        float xr[8] = {xv0.x, xv0.y, xv0.z, xv0.w, xv1.x, xv1.y, xv1.z, xv1.w};
        float wc[8] = {wv0.x, wv0.y, wv0.z, wv0.w, wv1.x, wv1.y, wv1.z, wv1.w};
#pragma unroll
        for (int ri = 0; ri < 8; ++ri)
#pragma unroll
          for (int cj = 0; cj < 8; ++cj)
            acc[ri][cj] = fmaf(xr[ri], wc[cj], acc[ri][cj]);
      }
    }

    // per-chunk min-merge (codes ascending -> lowest-index tie-break)
    {
#pragma clang fp contract(off)
      float sxr[8];
#pragma unroll
      for (int ri = 0; ri < 8; ++ri) sxr[ri] = sx[n0 + rt * 8 + ri];
#pragma unroll
      for (int cj = 0; cj < 8; ++cj) {
        const int code = code0 + ct * 8 + cj;
        const float swv = sw[code];
        const float codef = (float)code;
#pragma unroll
        for (int ri = 0; ri < 8; ++ri) {
          const float tmp = sxr[ri] - 2.0f * acc[ri][cj];  // fl(sx - 2G)
          const float key = tmp + swv;                     // fl(.. + sw)
          if (key < bk[ri] || (key == bk[ri] && codef < bi[ri])) {
            bk[ri] = key; bi[ri] = codef;
          }
        }
      }
    }
  }

  // cross-thread reduction: 32 code-group slabs per row, overlaid on ws
  __syncthreads();
  float* redk = ws;                    // 32*64 floats
  float* redi = ws + 32 * MT;          // 32*64 floats (codes as float, exact)
#pragma unroll
  for (int ri = 0; ri < 8; ++ri) {
    const int row = rt * 8 + ri;
    redk[ct * MT + row] = bk[ri];
    redi[ct * MT + row] = bi[ri];
  }
  __syncthreads();
  if (t < MT) {
    float k0 = redk[t]; float i0 = redi[t];
    for (int q = 1; q < 32; ++q) {     // ascending ct -> ascending codes
      const float kq = redk[q * MT + t];
      const float iq = redi[q * MT + t];
      if (kq < k0 || (kq == k0 && iq < i0)) { k0 = kq; i0 = iq; }
    }
    oidx[n0 + t] = i0;   // idx output region read back as fp32
  }
}

// ---------------------------------------------------------------------------
// Epilogue: block = (b, 64-hw tile). Stage the 64 gathered w-rows into LDS
// (wt[c][r], stride 65 -> 2-way banks, free), then fully-coalesced vf4
// global reads/writes for q and ste = fl(fl(q - x) + x).
// ---------------------------------------------------------------------------
#define WT_S 65

__global__ void k_epilogue(const float* __restrict__ x, const float* __restrict__ w,
                           const float* __restrict__ oidx, float* __restrict__ out) {
#pragma clang fp contract(off)
  __shared__ int   idxs[MT];
  __shared__ float wt[CODE_DIM * WT_S];   // wt[c][r], 66560 B

  const int t   = threadIdx.x;
  const int n0  = blockIdx.x * MT;
  const int b   = n0 >> 10;
  const int hw0 = n0 & 1023;

  if (t < MT) idxs[t] = (int)oidx[n0 + t];
  __syncthreads();

  // stage wt: jobs j -> (r = j&63, cq = j>>6); lanes span r -> per-lane 16-B
  // gathers from 64 w-rows (L1/L2 absorb; each row consumed fully by the
  // 4 sibling threads), LDS writes bank=(c+r)%32 with r spanning -> free.
#pragma unroll
  for (int i = 0; i < 16; ++i) {
    const int j  = t + 256 * i;
    const int r  = j & 63;
    const int cq = j >> 6;     // 0..63
    vf4 v = *(const vf4*)(w + (size_t)idxs[r] * CODE_DIM + cq * 4);
    wt[(cq * 4 + 0) * WT_S + r] = v.x;
    wt[(cq * 4 + 1) * WT_S + r] = v.y;
    wt[(cq * 4 + 2) * WT_S + r] = v.z;
    wt[(cq * 4 + 3) * WT_S + r] = v.w;
  }
  __syncthreads();

  // outputs: jobs j -> (c = j>>4, rq = j&15); global vf4 fully coalesced
#pragma unroll
  for (int i = 0; i < 16; ++i) {
    const int j  = t + 256 * i;
    const int c  = j >> 4;     // 0..255
    const int rq = j & 15;
    const size_t off = (size_t)(b * CODE_DIM + c) * HWSZ + hw0 + rq * 4;
    vf4 xv = *(const vf4*)(x + off);
    vf4 q, s;
#pragma unroll
    for (int u = 0; u < 4; ++u) {
      const float qv = wt[c * WT_S + rq * 4 + u];
      q[u] = qv;
      const float d = qv - xv[u];
      s[u] = d + xv[u];
    }
    *(vf4*)(out + off) = q;
    *(vf4*)(out + (size_t)QELEMS + off) = s;
  }
}

extern "C" void kernel_launch(void* const* d_in, const int* in_sizes, int n_in,
                              void* d_out, int out_size, void* d_ws, size_t ws_size,
                              hipStream_t stream) {
  const float* x = (const float*)d_in[0];   // (64,256,32,32) fp32
  const float* w = (const float*)d_in[1];   // (1024,256) fp32
  float* out  = (float*)d_out;
  float* oidx = out + 2 * (size_t)QELEMS;          // idx region (written as float)
  // scratch for sx/sw lives inside the ste region; epilogue (which runs after
  // k_argmin completes, stream-ordered) overwrites it later
  float* sx = out + (size_t)QELEMS;                // 65536 floats
  float* sw = out + (size_t)QELEMS + NROWS;        // 1024 floats

  k_sumsq_w<<<CODE_SIZE / 256, 256, 0, stream>>>(w, sw);
  k_sumsq_x<<<NROWS / 256, 256, 0, stream>>>(x, sx);
  k_argmin<<<NROWS / MT, 256, 0, stream>>>(x, w, sx, sw, oidx);
  k_epilogue<<<NROWS / MT, 256, 0, stream>>>(x, w, oidx, out);
}

// Round 6
// 627.526 us; speedup vs baseline: 2.8476x; 1.4393x over previous
//
#include <hip/hip_runtime.h>
#include <math.h>

typedef float vf4 __attribute__((ext_vector_type(4)));

#define CODE_SIZE 1024
#define CODE_DIM  256
#define BB        64
#define HWSZ      1024                       // H*W = 32*32
#define NROWS     (BB * HWSZ)                // 65536
#define QELEMS    (BB * CODE_DIM * HWSZ)     // 16777216

// ---------------------------------------------------------------------------
// sw[code] = numpy-pairwise sum of fl(w*w) over 256 contiguous elements.
// ---------------------------------------------------------------------------
__global__ void k_sumsq_w(const float* __restrict__ w, float* __restrict__ sw) {
#pragma clang fp contract(off)
  const int code = blockIdx.x * blockDim.x + threadIdx.x;
  if (code >= CODE_SIZE) return;
  const float* row = w + (size_t)code * CODE_DIM;
  float halves[2];
  for (int h = 0; h < 2; ++h) {
    const float* p = row + h * 128;
    float r[8];
#pragma unroll
    for (int j = 0; j < 8; ++j) { float v = p[j]; r[j] = v * v; }
    for (int i = 8; i < 128; i += 8) {
#pragma unroll
      for (int j = 0; j < 8; ++j) { float v = p[i + j]; r[j] += v * v; }
    }
    halves[h] = ((r[0] + r[1]) + (r[2] + r[3])) + ((r[4] + r[5]) + (r[6] + r[7]));
  }
  sw[code] = halves[0] + halves[1];
}

// sx[n] = same pairwise over fl(x*x), x strided by HWSZ along channel dim.
__global__ void k_sumsq_x(const float* __restrict__ x, float* __restrict__ sx) {
#pragma clang fp contract(off)
  const int n = blockIdx.x * blockDim.x + threadIdx.x;   // 0..65535
  const int b = n >> 10, hw = n & 1023;
  const float* p = x + (size_t)b * CODE_DIM * HWSZ + hw;
  float halves[2];
  for (int h = 0; h < 2; ++h) {
    const float* q = p + (size_t)(h * 128) * HWSZ;
    float r[8];
#pragma unroll
    for (int j = 0; j < 8; ++j) { float v = q[(size_t)j * HWSZ]; r[j] = v * v; }
    for (int i = 8; i < 128; i += 8) {
#pragma unroll
      for (int j = 0; j < 8; ++j) { float v = q[(size_t)(i + j) * HWSZ]; r[j] += v * v; }
    }
    halves[h] = ((r[0] + r[1]) + (r[2] + r[3])) + ((r[4] + r[5]) + (r[6] + r[7]));
  }
  sx[n] = halves[0] + halves[1];
}

// ---------------------------------------------------------------------------
// GEMM-argmin v5: round-0 skeleton (proven, bit-exact) with an 8x16 thread
// tile. Round 0 was DS-throughput-bound: 1.0 B LDS per lane-FMA vs LDS
// ~85 B/cy/CU supply against 128 B/cy demand -> VALUBusy 66.6%. 8x16 needs
// 4*(8+16)/128 = 0.75 B/FMA -> DS floor ~248us (vs ~330).
//  - acc[8][16] = 128 regs: lives in AGPRs (unified file; round-0 evidence:
//    VGPR_Count 64 = acc[64] in AGPR + 64 VGPR = exactly the (256,4) cap,
//    at full VALU rate). (256,2) -> 256-reg combined cap: ~190 used, NO
//    spill (round-1 lesson: cap 128 spilled; v3/v4 lesson: don't exceed
//    what RA can hold).
//  - Bank fix: a contiguous 16-code slab would put even-ct lanes all on
//    banks 0-3 (4-way, 1.58x — erases the win). Thread's 16 codes = two
//    8-code slabs 256 apart (ct*8 and 256+ct*8): both reads keep the
//    2-way-free round-0 pattern.
//  - NTC=512 codes/chunk, NCH=2; ws staging: thread t owns codes t, t+256.
// Numerics: bit-identical to round 0 — same sequential fmaf chain per
// (row,code) over k=0..255 (chunk-outer, kc-inner), key = fl(fl(sx-2G)+sw)
// contract-off, codes ascending per thread (slabA < slabB), lexicographic
// (key,idx) merges -> lowest-index tie-break. absmax must stay 0.0.
// LDS: xs 8KB + ws 64KB = 73728 B -> 2 blocks/CU (8 waves). DS per k-step:
// 8 waves x 6 ds_read_b128 x 12cy = 576 cy vs per-SIMD VALU 512 -> ~89%.
// ---------------------------------------------------------------------------
#define MT  64
#define NTC 512
#define NCH (CODE_SIZE / NTC)   // 2
#define KC  32

__launch_bounds__(256, 2)
__global__ void k_argmin(const float* __restrict__ x, const float* __restrict__ w,
                         const float* __restrict__ sx, const float* __restrict__ sw,
                         float* __restrict__ oidx) {
  __shared__ float xs[KC * MT];    // [k][row],  8 KB
  __shared__ float ws[KC * NTC];   // [k][code], 64 KB; overlaid by reduction

  const int t   = threadIdx.x;
  const int n0  = blockIdx.x * MT;
  const int b   = n0 >> 10;
  const int hw0 = n0 & 1023;
  const int rt  = t & 7;     // rows rt*8 .. rt*8+7
  const int ct  = t >> 3;    // code-group 0..31

  float bk[8]; float bi[8];
#pragma unroll
  for (int ri = 0; ri < 8; ++ri) { bk[ri] = INFINITY; bi[ri] = (float)CODE_SIZE; }

  for (int chunk = 0; chunk < NCH; ++chunk) {
    const int code0 = chunk * NTC;

    float acc[8][16];
#pragma unroll
    for (int ri = 0; ri < 8; ++ri)
#pragma unroll
      for (int cj = 0; cj < 16; ++cj) acc[ri][cj] = 0.0f;

    for (int kc = 0; kc < CODE_DIM / KC; ++kc) {
      const int kbase = kc * KC;
      __syncthreads();   // protect xs/ws from previous step's readers
      // stage xs[k][r]: 512 vf4 jobs, coalesced 256-B segments per k-row
#pragma unroll
      for (int i = 0; i < 2; ++i) {
        const int j  = t + 256 * i;
        const int k  = j >> 4;      // 0..31
        const int rq = j & 15;      // row quad
        vf4 v = *(const vf4*)(x + ((size_t)(b * CODE_DIM + kbase + k) * HWSZ + hw0 + rq * 4));
        *(vf4*)(xs + k * MT + rq * 4) = v;
      }
      // stage ws[k][code]: thread t owns codes t and t+256; row-contiguous
      // global reads (w is 1 MB, L1/L2-hot); LDS writes consecutive -> 2-way
#pragma unroll
      for (int s = 0; s < 2; ++s) {
        const int code = t + s * 256;
        const float* wr = w + (size_t)(code0 + code) * CODE_DIM + kbase;
#pragma unroll
        for (int q = 0; q < 8; ++q) {
          vf4 v = *(const vf4*)(wr + q * 4);
          ws[(q * 4 + 0) * NTC + code] = v.x;
          ws[(q * 4 + 1) * NTC + code] = v.y;
          ws[(q * 4 + 2) * NTC + code] = v.z;
          ws[(q * 4 + 3) * NTC + code] = v.w;
        }
      }
      __syncthreads();

      const float* xp  = xs + rt * 8;
      const float* wpA = ws + ct * 8;          // slab A: codes ct*8..+7
      const float* wpB = ws + 256 + ct * 8;    // slab B: codes 256+ct*8..+7
#pragma unroll 4
      for (int k = 0; k < KC; ++k) {
        vf4 xv0 = *(const vf4*)(xp + k * MT);
        vf4 xv1 = *(const vf4*)(xp + k * MT + 4);
        vf4 wa0 = *(const vf4*)(wpA + k * NTC);
        vf4 wa1 = *(const vf4*)(wpA + k * NTC + 4);
        vf4 wb0 = *(const vf4*)(wpB + k * NTC);
        vf4 wb1 = *(const vf4*)(wpB + k * NTC + 4);
        float xr[8]  = {xv0.x, xv0.y, xv0.z, xv0.w, xv1.x, xv1.y, xv1.z, xv1.w};
        float wc[16] = {wa0.x, wa0.y, wa0.z, wa0.w, wa1.x, wa1.y, wa1.z, wa1.w,
                        wb0.x, wb0.y, wb0.z, wb0.w, wb1.x, wb1.y, wb1.z, wb1.w};
#pragma unroll
        for (int ri = 0; ri < 8; ++ri)
#pragma unroll
          for (int cj = 0; cj < 16; ++cj)
            acc[ri][cj] = fmaf(xr[ri], wc[cj], acc[ri][cj]);
      }
    }

    // per-chunk min-merge; per-thread codes ascending (slab A then B)
    {
#pragma clang fp contract(off)
      float sxr[8];
#pragma unroll
      for (int ri = 0; ri < 8; ++ri) sxr[ri] = sx[n0 + rt * 8 + ri];
#pragma unroll
      for (int slab = 0; slab < 2; ++slab) {
#pragma unroll
        for (int cj = 0; cj < 8; ++cj) {
          const int code = code0 + slab * 256 + ct * 8 + cj;
          const float swv = sw[code];
          const float codef = (float)code;
#pragma unroll
          for (int ri = 0; ri < 8; ++ri) {
            const float tmp = sxr[ri] - 2.0f * acc[ri][slab * 8 + cj]; // fl(sx-2G)
            const float key = tmp + swv;                               // fl(..+sw)
            if (key < bk[ri] || (key == bk[ri] && codef < bi[ri])) {
              bk[ri] = key; bi[ri] = codef;
            }
          }
        }
      }
    }
  }

  // cross-thread reduction: 32 thread-slabs per row, overlaid on ws.
  // Threads hold disjoint code sets; lexicographic (key, idx) min is
  // order-independent and keeps the lowest index on ties.
  __syncthreads();
  float* redk = ws;                    // 32*64 floats
  float* redi = ws + 32 * MT;          // 32*64 floats (codes as float, exact)
#pragma unroll
  for (int ri = 0; ri < 8; ++ri) {
    const int row = rt * 8 + ri;
    redk[ct * MT + row] = bk[ri];
    redi[ct * MT + row] = bi[ri];
  }
  __syncthreads();
  if (t < MT) {
    float k0 = redk[t]; float i0 = redi[t];
    for (int q = 1; q < 32; ++q) {
      const float kq = redk[q * MT + t];
      const float iq = redi[q * MT + t];
      if (kq < k0 || (kq == k0 && iq < i0)) { k0 = kq; i0 = iq; }
    }
    oidx[n0 + t] = i0;   // idx output region read back as fp32
  }
}

// ---------------------------------------------------------------------------
// Epilogue: block = (b, 64-hw tile). Stage the 64 gathered w-rows into LDS
// (wt[c][r], stride 65 -> 2-way banks, free), then fully-coalesced vf4
// global reads/writes for q and ste = fl(fl(q - x) + x).
// ---------------------------------------------------------------------------
#define WT_S 65

__global__ void k_epilogue(const float* __restrict__ x, const float* __restrict__ w,
                           const float* __restrict__ oidx, float* __restrict__ out) {
#pragma clang fp contract(off)
  __shared__ int   idxs[MT];
  __shared__ float wt[CODE_DIM * WT_S];   // wt[c][r], 66560 B

  const int t   = threadIdx.x;
  const int n0  = blockIdx.x * MT;
  const int b   = n0 >> 10;
  const int hw0 = n0 & 1023;

  if (t < MT) idxs[t] = (int)oidx[n0 + t];
  __syncthreads();

  // stage wt: jobs j -> (r = j&63, cq = j>>6); lanes span r -> per-lane 16-B
  // gathers from 64 w-rows (L1/L2 absorb; each row consumed fully by the
  // 4 sibling threads), LDS writes bank=(c+r)%32 with r spanning -> free.
#pragma unroll
  for (int i = 0; i < 16; ++i) {
    const int j  = t + 256 * i;
    const int r  = j & 63;
    const int cq = j >> 6;     // 0..63
    vf4 v = *(const vf4*)(w + (size_t)idxs[r] * CODE_DIM + cq * 4);
    wt[(cq * 4 + 0) * WT_S + r] = v.x;
    wt[(cq * 4 + 1) * WT_S + r] = v.y;
    wt[(cq * 4 + 2) * WT_S + r] = v.z;
    wt[(cq * 4 + 3) * WT_S + r] = v.w;
  }
  __syncthreads();

  // outputs: jobs j -> (c = j>>4, rq = j&15); global vf4 fully coalesced
#pragma unroll
  for (int i = 0; i < 16; ++i) {
    const int j  = t + 256 * i;
    const int c  = j >> 4;     // 0..255
    const int rq = j & 15;
    const size_t off = (size_t)(b * CODE_DIM + c) * HWSZ + hw0 + rq * 4;
    vf4 xv = *(const vf4*)(x + off);
    vf4 q, s;
#pragma unroll
    for (int u = 0; u < 4; ++u) {
      const float qv = wt[c * WT_S + rq * 4 + u];
      q[u] = qv;
      const float d = qv - xv[u];
      s[u] = d + xv[u];
    }
    *(vf4*)(out + off) = q;
    *(vf4*)(out + (size_t)QELEMS + off) = s;
  }
}

extern "C" void kernel_launch(void* const* d_in, const int* in_sizes, int n_in,
                              void* d_out, int out_size, void* d_ws, size_t ws_size,
                              hipStream_t stream) {
  const float* x = (const float*)d_in[0];   // (64,256,32,32) fp32
  const float* w = (const float*)d_in[1];   // (1024,256) fp32
  float* out  = (float*)d_out;
  float* oidx = out + 2 * (size_t)QELEMS;          // idx region (written as float)
  // scratch for sx/sw lives inside the ste region; epilogue (which runs after
  // k_argmin completes, stream-ordered) overwrites it later
  float* sx = out + (size_t)QELEMS;                // 65536 floats
  float* sw = out + (size_t)QELEMS + NROWS;        // 1024 floats

  k_sumsq_w<<<CODE_SIZE / 256, 256, 0, stream>>>(w, sw);
  k_sumsq_x<<<NROWS / 256, 256, 0, stream>>>(x, sx);
  k_argmin<<<NROWS / MT, 256, 0, stream>>>(x, w, sx, sw, oidx);
  k_epilogue<<<NROWS / MT, 256, 0, stream>>>(x, w, oidx, out);
}

// Round 8
// 613.469 us; speedup vs baseline: 2.9128x; 1.0229x over previous
//
#include <hip/hip_runtime.h>
#include <math.h>

typedef float vf4 __attribute__((ext_vector_type(4)));

#define CODE_SIZE 1024
#define CODE_DIM  256
#define BB        64
#define HWSZ      1024                       // H*W = 32*32
#define NROWS     (BB * HWSZ)                // 65536
#define QELEMS    (BB * CODE_DIM * HWSZ)     // 16777216

// ---------------------------------------------------------------------------
// sw[code] = numpy-pairwise sum of fl(w*w) over 256 contiguous elements.
// ---------------------------------------------------------------------------
__global__ void k_sumsq_w(const float* __restrict__ w, float* __restrict__ sw) {
#pragma clang fp contract(off)
  const int code = blockIdx.x * blockDim.x + threadIdx.x;
  if (code >= CODE_SIZE) return;
  const float* row = w + (size_t)code * CODE_DIM;
  float halves[2];
  for (int h = 0; h < 2; ++h) {
    const float* p = row + h * 128;
    float r[8];
#pragma unroll
    for (int j = 0; j < 8; ++j) { float v = p[j]; r[j] = v * v; }
    for (int i = 8; i < 128; i += 8) {
#pragma unroll
      for (int j = 0; j < 8; ++j) { float v = p[i + j]; r[j] += v * v; }
    }
    halves[h] = ((r[0] + r[1]) + (r[2] + r[3])) + ((r[4] + r[5]) + (r[6] + r[7]));
  }
  sw[code] = halves[0] + halves[1];
}

// sx[n] = same pairwise over fl(x*x), x strided by HWSZ along channel dim.
__global__ void k_sumsq_x(const float* __restrict__ x, float* __restrict__ sx) {
#pragma clang fp contract(off)
  const int n = blockIdx.x * blockDim.x + threadIdx.x;   // 0..65535
  const int b = n >> 10, hw = n & 1023;
  const float* p = x + (size_t)b * CODE_DIM * HWSZ + hw;
  float halves[2];
  for (int h = 0; h < 2; ++h) {
    const float* q = p + (size_t)(h * 128) * HWSZ;
    float r[8];
#pragma unroll
    for (int j = 0; j < 8; ++j) { float v = q[(size_t)j * HWSZ]; r[j] = v * v; }
    for (int i = 8; i < 128; i += 8) {
#pragma unroll
      for (int j = 0; j < 8; ++j) { float v = q[(size_t)(i + j) * HWSZ]; r[j] += v * v; }
    }
    halves[h] = ((r[0] + r[1]) + (r[2] + r[3])) + ((r[4] + r[5]) + (r[6] + r[7]));
  }
  sx[n] = halves[0] + halves[1];
}

// ---------------------------------------------------------------------------
// GEMM-argmin v6b (= v6 with lambdas inlined as macros; no functional change;
// round-7 bench died with no counters twice — infra-flake hypothesis, see
// journal; tripwire: a 3rd container death implicates global_load_lds and
// round 9 pivots to reg-staged).
// Design: 16x8 thread tile (0.75 B LDS/FMA), MT=128, NTC=256, built for the
// 2-waves/SIMD regime the 128-acc tile forces:
//  - grid = 512 = exactly 2 blocks/CU, fully resident, no tail.
//  - x staged via global_load_lds (16B) into DOUBLE-BUFFERED xs; issue for
//    step kc+1 at compute start -> ~8k cy of FMA hides the latency; the
//    compiler's vmcnt(0)-before-barrier is the completion guarantee.
//  - w staged via register prefetch (8 vf4 = 32 regs) issued at compute
//    start, consumed by a pure reg->LDS write between the barriers. Budget:
//    2 waves/SIMD -> 256-reg cap; acc 128 + bk/bi 32 + pwv 32 + frags ~230.
//    asm keep-alive after compute pins the loads above the next barrier.
//  - rows per thread = rt*4 + q*32 + j: the 4 x-frag ds_read_b128 hit 8
//    distinct bank-quads covering all 32 banks (8-lane broadcast each) ->
//    conflict-free; w-frag reads 2-way -> free. k-loop pinned unroll 1
//    (trip-32 full-unroll would explode regs — rounds 1/4 lesson).
// Round-6 lesson: 8 waves/CU is survivable only if NOTHING waits vmcnt(0)
// on fresh loads inside the barrier pair; here zero global ops sit between
// the barriers.
// Numerics: bit-identical to round 0 — per-(row,code) sequential fmaf
// chain over k=0..255 (chunk-outer, kc-inner, k ascending), key =
// fl(fl(sx-2G)+sw) contract-off, codes ascending per thread, lexicographic
// (key,idx) merges -> lowest-index tie-break. absmax must stay 0.0.
// LDS: xs 2x16KB + ws 32KB = 65536 B -> 2 blocks/CU = 128 KB.
// ---------------------------------------------------------------------------
#define MT  128
#define NTC 256
#define NCH (CODE_SIZE / NTC)   // 4
#define KC  32

// issue x gloads for kc-step into xs[buf]: j -> (k=j>>5, rq=j&31);
// LDS dest = base + j*16B is lane-linear -> wave-uniform-base constraint OK
#define ISSUE_X(kc_, buf_)                                                     \
  do {                                                                         \
    const int kbase_ = (kc_) * KC;                                             \
    _Pragma("unroll")                                                          \
    for (int i_ = 0; i_ < 4; ++i_) {                                           \
      const int j_  = t + 256 * i_;                                            \
      const int k_  = j_ >> 5;                                                 \
      const int rq_ = j_ & 31;                                                 \
      const float* gp_ = x + ((size_t)(b * CODE_DIM + kbase_ + k_) * HWSZ      \
                              + hw0 + rq_ * 4);                                \
      __builtin_amdgcn_global_load_lds(                                        \
          (const __attribute__((address_space(1))) void*)gp_,                  \
          (__attribute__((address_space(3))) void*)&xs[buf_][j_ * 4],          \
          16, 0, 0);                                                           \
    }                                                                          \
  } while (0)

// issue w reg-prefetch for (chunk, kc): thread t owns code chunk*NTC + t
#define ISSUE_W(chunk_, kc_)                                                   \
  do {                                                                         \
    const float* wr_ = w + (size_t)((chunk_) * NTC + t) * CODE_DIM             \
                         + (kc_) * KC;                                         \
    _Pragma("unroll")                                                          \
    for (int q_ = 0; q_ < 8; ++q_) pwv[q_] = *(const vf4*)(wr_ + q_ * 4);      \
  } while (0)

__launch_bounds__(256, 2)
__global__ void k_argmin(const float* __restrict__ x, const float* __restrict__ w,
                         const float* __restrict__ sx, const float* __restrict__ sw,
                         float* __restrict__ oidx) {
  __shared__ float xs[2][KC * MT];   // [buf][k][row], 2 x 16 KB
  __shared__ float ws[KC * NTC];     // [k][code], 32 KB; overlaid by reduction

  const int t   = threadIdx.x;
  const int n0  = blockIdx.x * MT;   // 128 | 1024 -> never straddles b
  const int b   = n0 >> 10;
  const int hw0 = n0 & 1023;
  const int rt  = t & 7;     // row-group: rows rt*4 + q*32 + j
  const int ct  = t >> 3;    // code-group 0..31: codes ct*8..ct*8+7 per chunk

  vf4 pwv[8];

  float bk[16]; float bi[16];
#pragma unroll
  for (int ri = 0; ri < 16; ++ri) { bk[ri] = INFINITY; bi[ri] = (float)CODE_SIZE; }

  ISSUE_W(0, 0);
  ISSUE_X(0, 0);
  int cur = 0;

  for (int chunk = 0; chunk < NCH; ++chunk) {
    const int code0 = chunk * NTC;

    float acc[16][8];
#pragma unroll
    for (int ri = 0; ri < 16; ++ri)
#pragma unroll
      for (int cj = 0; cj < 8; ++cj) acc[ri][cj] = 0.0f;

    for (int kc = 0; kc < CODE_DIM / KC; ++kc) {
      __syncthreads();   // A: prev readers done with ws; xs[cur] gloads + pwv drained
      // ws[k][code] write phase: pure reg->LDS; banks t%32, 2-way -> free
#pragma unroll
      for (int q = 0; q < 8; ++q) {
        ws[(q * 4 + 0) * NTC + t] = pwv[q].x;
        ws[(q * 4 + 1) * NTC + t] = pwv[q].y;
        ws[(q * 4 + 2) * NTC + t] = pwv[q].z;
        ws[(q * 4 + 3) * NTC + t] = pwv[q].w;
      }
      __syncthreads();   // B: ws visible

      // issue next step's staging NOW; latency hides under the FMA phase.
      // Tail wraps to (chunk+1, 0) / (0,0) — harmless valid loads.
      {
        int nkc = kc + 1, nch = chunk;
        if (nkc == CODE_DIM / KC) { nkc = 0; nch = (chunk + 1) & (NCH - 1); }
        ISSUE_X(nkc, cur ^ 1);
        ISSUE_W(nch, nkc);
      }

      const float* xp = &xs[cur][0];
      const float* wp = ws + ct * 8;
#pragma unroll 1
      for (int k = 0; k < KC; ++k) {
        vf4 xq0 = *(const vf4*)(xp + k * MT + rt * 4);
        vf4 xq1 = *(const vf4*)(xp + k * MT + rt * 4 + 32);
        vf4 xq2 = *(const vf4*)(xp + k * MT + rt * 4 + 64);
        vf4 xq3 = *(const vf4*)(xp + k * MT + rt * 4 + 96);
        vf4 wv0 = *(const vf4*)(wp + k * NTC);
        vf4 wv1 = *(const vf4*)(wp + k * NTC + 4);
        float xr[16] = {xq0.x, xq0.y, xq0.z, xq0.w, xq1.x, xq1.y, xq1.z, xq1.w,
                        xq2.x, xq2.y, xq2.z, xq2.w, xq3.x, xq3.y, xq3.z, xq3.w};
        float wc[8]  = {wv0.x, wv0.y, wv0.z, wv0.w, wv1.x, wv1.y, wv1.z, wv1.w};
#pragma unroll
        for (int ri = 0; ri < 16; ++ri)
#pragma unroll
          for (int cj = 0; cj < 8; ++cj)
            acc[ri][cj] = fmaf(xr[ri], wc[cj], acc[ri][cj]);
      }
      // keep-alive: pwv must be complete here -> loads can't sink below the
      // compute phase (bounded cost even if the scheduler issues them late)
      asm volatile("" :: "v"(pwv[0]), "v"(pwv[1]), "v"(pwv[2]), "v"(pwv[3]),
                         "v"(pwv[4]), "v"(pwv[5]), "v"(pwv[6]), "v"(pwv[7]));
      cur ^= 1;
    }

    // per-chunk min-merge (codes ascending per thread -> lowest-index ties)
    {
#pragma clang fp contract(off)
      float sxr[16];
#pragma unroll
      for (int q = 0; q < 4; ++q)
#pragma unroll
        for (int j = 0; j < 4; ++j)
          sxr[q * 4 + j] = sx[n0 + rt * 4 + q * 32 + j];
#pragma unroll
      for (int cj = 0; cj < 8; ++cj) {
        const int code = code0 + ct * 8 + cj;
        const float swv = sw[code];
        const float codef = (float)code;
#pragma unroll
        for (int ri = 0; ri < 16; ++ri) {
          const float tmp = sxr[ri] - 2.0f * acc[ri][cj];  // fl(sx - 2G)
          const float key = tmp + swv;                     // fl(.. + sw)
          if (key < bk[ri] || (key == bk[ri] && codef < bi[ri])) {
            bk[ri] = key; bi[ri] = codef;
          }
        }
      }
    }
  }

  // cross-thread reduction: 32 code-group slabs per row, overlaid on ws
  __syncthreads();
  float* redk = ws;                    // 32*128 floats (16 KB)
  float* redi = ws + 32 * MT;          // 32*128 floats (codes as float, exact)
#pragma unroll
  for (int q = 0; q < 4; ++q)
#pragma unroll
    for (int j = 0; j < 4; ++j) {
      const int row = rt * 4 + q * 32 + j;
      redk[ct * MT + row] = bk[q * 4 + j];
      redi[ct * MT + row] = bi[q * 4 + j];
    }
  __syncthreads();
  if (t < MT) {
    float k0 = redk[t]; float i0 = redi[t];
    for (int q = 1; q < 32; ++q) {     // ascending ct -> ascending codes
      const float kq = redk[q * MT + t];
      const float iq = redi[q * MT + t];
      if (kq < k0 || (kq == k0 && iq < i0)) { k0 = kq; i0 = iq; }
    }
    oidx[n0 + t] = i0;   // idx output region read back as fp32
  }
}

// ---------------------------------------------------------------------------
// Epilogue v2: block = 32-hw tile (was 64) -> wt 33 KB -> 4 blocks/CU
// (was 2; this kernel streams 192 MB and was occupancy-starved). Stage the
// 32 gathered w-rows into LDS (wt[c][r], stride 33 -> (c+r)%32 banks,
// conflict-free), then fully-coalesced vf4 global reads/writes for q and
// ste = fl(fl(q - x) + x).
// ---------------------------------------------------------------------------
#define MTE  32
#define WT_S 33

__global__ void k_epilogue(const float* __restrict__ x, const float* __restrict__ w,
                           const float* __restrict__ oidx, float* __restrict__ out) {
#pragma clang fp contract(off)
  __shared__ int   idxs[MTE];
  __shared__ float wt[CODE_DIM * WT_S];   // wt[c][r], 33792 B

  const int t   = threadIdx.x;
  const int n0  = blockIdx.x * MTE;
  const int b   = n0 >> 10;
  const int hw0 = n0 & 1023;

  if (t < MTE) idxs[t] = (int)oidx[n0 + t];
  __syncthreads();

  // stage wt: jobs j -> (r = j&31, cq = j>>5); per-lane 16-B gathers from
  // 32 w-rows (L1/L2 absorb); LDS write bank = (4cq+u+r)%32, r spans -> free
#pragma unroll
  for (int i = 0; i < 8; ++i) {
    const int j  = t + 256 * i;
    const int r  = j & 31;
    const int cq = j >> 5;     // 0..63
    vf4 v = *(const vf4*)(w + (size_t)idxs[r] * CODE_DIM + cq * 4);
    wt[(cq * 4 + 0) * WT_S + r] = v.x;
    wt[(cq * 4 + 1) * WT_S + r] = v.y;
    wt[(cq * 4 + 2) * WT_S + r] = v.z;
    wt[(cq * 4 + 3) * WT_S + r] = v.w;
  }
  __syncthreads();

  // outputs: jobs j -> (c = j>>3, rq = j&7); global vf4 coalesced
  // (8 x 128-B segments per instr); wt read banks (c+4rq+u)%32 -> free
#pragma unroll
  for (int i = 0; i < 8; ++i) {
    const int j  = t + 256 * i;
    const int c  = j >> 3;     // 0..255
    const int rq = j & 7;
    const size_t off = (size_t)(b * CODE_DIM + c) * HWSZ + hw0 + rq * 4;
    vf4 xv = *(const vf4*)(x + off);
    vf4 q, s;
#pragma unroll
    for (int u = 0; u < 4; ++u) {
      const float qv = wt[c * WT_S + rq * 4 + u];
      q[u] = qv;
      const float d = qv - xv[u];
      s[u] = d + xv[u];
    }
    *(vf4*)(out + off) = q;
    *(vf4*)(out + (size_t)QELEMS + off) = s;
  }
}

extern "C" void kernel_launch(void* const* d_in, const int* in_sizes, int n_in,
                              void* d_out, int out_size, void* d_ws, size_t ws_size,
                              hipStream_t stream) {
  const float* x = (const float*)d_in[0];   // (64,256,32,32) fp32
  const float* w = (const float*)d_in[1];   // (1024,256) fp32
  float* out  = (float*)d_out;
  float* oidx = out + 2 * (size_t)QELEMS;          // idx region (written as float)
  // scratch for sx/sw lives inside the ste region; epilogue (which runs after
  // k_argmin completes, stream-ordered) overwrites it later
  float* sx = out + (size_t)QELEMS;                // 65536 floats
  float* sw = out + (size_t)QELEMS + NROWS;        // 1024 floats

  k_sumsq_w<<<CODE_SIZE / 256, 256, 0, stream>>>(w, sw);
  k_sumsq_x<<<NROWS / 256, 256, 0, stream>>>(x, sx);
  k_argmin<<<NROWS / MT, 256, 0, stream>>>(x, w, sx, sw, oidx);
  k_epilogue<<<NROWS / MTE, 256, 0, stream>>>(x, w, oidx, out);
}